// Round 8
// baseline (889.277 us; speedup 1.0000x reference)
//
#include <hip/hip_runtime.h>
#include <math.h>

using u16 = unsigned short;
using bf16x8 = __attribute__((ext_vector_type(8))) short;
using f32x4  = __attribute__((ext_vector_type(4))) float;

#define DEV static __device__ __forceinline__

DEV u16 f2bf(float f) {
  union { float f; unsigned u; } v; v.f = f;
  unsigned u = v.u + 0x7fffu + ((v.u >> 16) & 1u);
  return (u16)(u >> 16);
}

DEV void gload16(const void* g, void* l) {
  __builtin_amdgcn_global_load_lds(
      (const __attribute__((address_space(1))) void*)g,
      (__attribute__((address_space(3))) void*)l, 16, 0, 0);
}

// ---------------- prep kernels ----------------
__global__ void k_conv_bf16(const float* __restrict__ in, u16* __restrict__ out, int n) {
  int i = blockIdx.x * 256 + threadIdx.x;
  if (i < n) out[i] = f2bf(in[i]);
}

// in: f32 [K][Nin] row-major ; out: bf16 [Nout][K] (n-major).
// pack==1: n' = d2*48+j maps to n = d2*47+j for j<47, j==47 -> 0 (pad).
__global__ void k_transconv(const float* __restrict__ in, u16* __restrict__ out,
                            int K, int Nin, int Nout, int pack) {
  __shared__ float t[32][33];
  int kb = blockIdx.x * 32, nb = blockIdx.y * 32;
  int tx = threadIdx.x & 31, ty = threadIdx.x >> 5;  // 32 x 8
  #pragma unroll
  for (int i = 0; i < 4; ++i) {
    int k = kb + ty + i * 8;
    int no = nb + tx;
    float v = 0.f;
    if (k < K && no < Nout) {
      if (pack) {
        int r = no % 48;
        if (r < 47) v = in[(size_t)k * Nin + (no / 48) * 47 + r];
      } else {
        v = in[(size_t)k * Nin + no];
      }
    }
    t[ty + i * 8][tx] = v;
  }
  __syncthreads();
  #pragma unroll
  for (int i = 0; i < 4; ++i) {
    int no = nb + ty + i * 8;
    int k = kb + tx;
    if (no < Nout && k < K) out[(size_t)no * K + k] = f2bf(t[tx][ty + i * 8]);
  }
}

// ---------------- GEMM + ReLU (BM=128,BN=128,BK=32, 4 waves) for GEMM1/2 ----------------
__global__ __launch_bounds__(256)
void k_gemm_relu(const u16* __restrict__ A, const u16* __restrict__ Bt,
                 const float* __restrict__ bias, u16* __restrict__ C,
                 int N, int K) {
  constexpr int BM = 128, BN = 128, BK = 32;
  __shared__ __align__(16) u16 lds[(BM + BN) * BK];
  int tid = threadIdx.x, w = tid >> 6, lane = tid & 63;
  int bn = blockIdx.x, bm = blockIdx.y;
  int brow = bm * BM, bcol = bn * BN;
  int wm = w >> 1, wn = w & 1;
  int fr = lane & 15, fg = lane >> 4;
  f32x4 acc[4][4];
  #pragma unroll
  for (int i = 0; i < 4; ++i)
    #pragma unroll
    for (int j = 0; j < 4; ++j) acc[i][j] = (f32x4){0.f, 0.f, 0.f, 0.f};

  constexpr int ACH = BM * BK / 8;
  constexpr int CALLS = (BM + BN) * BK / 8 / 64;

  for (int kt = 0; kt < K; kt += BK) {
    for (int j = 0; j * 4 + w < CALLS; ++j) {
      int cb = (j * 4 + w) * 64;
      int c = cb + lane;
      const u16* g;
      if (c < ACH) {
        int row = c >> 2, c8 = c & 3;
        g = A + (size_t)(brow + row) * K + kt + c8 * 8;
      } else {
        int b = c - ACH;
        int nn = b >> 2, c8 = b & 3;
        g = Bt + (size_t)(bcol + nn) * K + kt + c8 * 8;
      }
      gload16(g, &lds[cb * 8]);
    }
    asm volatile("s_waitcnt vmcnt(0)" ::: "memory");
    __syncthreads();

    const u16* Al = lds;
    const u16* Bl = lds + BM * BK;
    bf16x8 af[4], bfr[4];
    #pragma unroll
    for (int mi = 0; mi < 4; ++mi)
      af[mi] = *(const bf16x8*)&Al[(wm * 64 + mi * 16 + fr) * BK + fg * 8];
    #pragma unroll
    for (int ni = 0; ni < 4; ++ni)
      bfr[ni] = *(const bf16x8*)&Bl[(wn * 64 + ni * 16 + fr) * BK + fg * 8];
    #pragma unroll
    for (int mi = 0; mi < 4; ++mi)
      #pragma unroll
      for (int ni = 0; ni < 4; ++ni)
        acc[mi][ni] = __builtin_amdgcn_mfma_f32_16x16x32_bf16(af[mi], bfr[ni], acc[mi][ni], 0, 0, 0);
    __syncthreads();
  }

  #pragma unroll
  for (int ni = 0; ni < 4; ++ni) {
    int col = bcol + wn * 64 + ni * 16 + fr;
    float bb = bias[col];
    #pragma unroll
    for (int mi = 0; mi < 4; ++mi) {
      #pragma unroll
      for (int q = 0; q < 4; ++q) {
        int row = brow + wm * 64 + mi * 16 + fg * 4 + q;
        float vv = acc[mi][ni][q] + bb;
        C[(size_t)row * N + col] = f2bf(vv > 0.f ? vv : 0.f);
      }
    }
  }
}

// ------- GEMM3 fused with spline: BM=192, BN=192, BK=64, 8 waves, 3-slot LDS ring -------
// LDS 147456 B = 3 slots x 49152 (A [192][64] bf16 at +0, B [192][64] at +24576),
// XOR chunk swizzle (R7-proven). Per wave (2wm x 4wn): 96x48 out, 18 ds_read_b128
// feed 36 MFMA per K-tile. DEPTH-2 pipeline: at top of tile t stage tile t+2 into
// slot (t+2)%3 (free since t-1's reads completed at t-1's end barrier); at end of
// tile t, vmcnt(6) guards tile t+1 (issued 2 tiles earlier, ~3800cyc lead >> 900cyc
// HBM latency). 6 uniform loads/thread/tile keeps the per-wave vmcnt ledger exact.
// One barrier per tile, no phase lockstep (R7's empirically-best loop + depth).
// M=16384 padded to 86 bm-blocks of 192: last block clamps A-row reads, epilogue
// guards grow<16384.
__global__ __launch_bounds__(512, 1)
void k_gemm3_fused(const u16* __restrict__ A, const u16* __restrict__ Bt,
                   const float* __restrict__ b2, const float* __restrict__ x2,
                   float* __restrict__ y2, float* __restrict__ ldpart) {
  extern __shared__ char smem[];
  const int tid = threadIdx.x, w = tid >> 6, lane = tid & 63;
  const int wm = w >> 2, wn = w & 3;
  const int fr = lane & 15, fg = lane >> 4;

  const int bid = blockIdx.x;                          // 5504 blocks = 86 bm x 64 bn
  const int bm = bid >> 6;
  const int bn = ((bid & 7) << 3) | ((bid >> 3) & 7);  // XCD-chunked L2 map (R5-proven)
  const int brow = bm * 192;

  // staging: unit u covers rows [64u,64u+64); thread -> (row=tid>>3, chunk=tid&7).
  // source chunk pre-XOR'd csrc = c ^ (row&7); LDS dest linear tid*16 (rule #21).
  const int csrc = (tid & 7) ^ ((tid >> 3) & 7);
  const u16* gA[3]; const u16* gB[3];
  #pragma unroll
  for (int u = 0; u < 3; ++u) {
    int rowA = brow + (tid >> 3) + 64 * u;
    rowA = rowA < 16383 ? rowA : 16383;                // clamp for last bm block
    gA[u] = A + (size_t)rowA * 1024 + csrc * 8;
    gB[u] = Bt + (size_t)(bn * 192 + (tid >> 3) + 64 * u) * 1024 + csrc * 8;
  }
  const int ldst = tid * 16;

#define STAGE(t1, sbase) {                                           \
    const size_t ko_ = (size_t)(t1) * 64;                            \
    char* p_ = smem + (sbase);                                       \
    gload16(gA[0] + ko_, p_ + ldst);                                 \
    gload16(gA[1] + ko_, p_ + 8192 + ldst);                          \
    gload16(gA[2] + ko_, p_ + 16384 + ldst);                         \
    gload16(gB[0] + ko_, p_ + 24576 + ldst);                         \
    gload16(gB[1] + ko_, p_ + 32768 + ldst);                         \
    gload16(gB[2] + ko_, p_ + 40960 + ldst); }

  // swizzled read chunk offsets: chunk = (kk*4+fg) ^ (row&7), row&7 == fr&7
  const int sc0 = ((fg ^ (fr & 7)) << 4);
  const int sc1 = (((4 + fg) ^ (fr & 7)) << 4);

  f32x4 acc[6][3];
  #pragma unroll
  for (int m = 0; m < 6; ++m)
    #pragma unroll
    for (int n = 0; n < 3; ++n) acc[m][n] = (f32x4){0.f, 0.f, 0.f, 0.f};

#define COMPUTE(sbase) {                                             \
    const char* Ab_ = smem + (sbase);                                \
    const char* Bb_ = smem + (sbase) + 24576;                        \
    bf16x8 b0[3], b1[3];                                             \
    _Pragma("unroll")                                                \
    for (int n_ = 0; n_ < 3; ++n_) {                                 \
      const char* bp_ = Bb_ + (wn * 48 + n_ * 16 + fr) * 128;        \
      b0[n_] = *(const bf16x8*)(bp_ + sc0);                          \
      b1[n_] = *(const bf16x8*)(bp_ + sc1);                          \
    }                                                                \
    __builtin_amdgcn_s_setprio(1);                                   \
    _Pragma("unroll")                                                \
    for (int m_ = 0; m_ < 6; ++m_) {                                 \
      const char* ap_ = Ab_ + (wm * 96 + m_ * 16 + fr) * 128;        \
      bf16x8 a0_ = *(const bf16x8*)(ap_ + sc0);                      \
      bf16x8 a1_ = *(const bf16x8*)(ap_ + sc1);                      \
      _Pragma("unroll")                                              \
      for (int n_ = 0; n_ < 3; ++n_) {                               \
        acc[m_][n_] = __builtin_amdgcn_mfma_f32_16x16x32_bf16(a0_, b0[n_], acc[m_][n_], 0, 0, 0); \
        acc[m_][n_] = __builtin_amdgcn_mfma_f32_16x16x32_bf16(a1_, b1[n_], acc[m_][n_], 0, 0, 0); \
      }                                                              \
    }                                                                \
    __builtin_amdgcn_s_setprio(0); }

#define VMW(n) asm volatile("s_waitcnt vmcnt(" #n ")" ::: "memory")

  // prologue: fill slots 0,1 (tiles 0,1); wait tile 0 only (6 of 12 outstanding)
  STAGE(0, 0); STAGE(1, 49152);
  VMW(6);
  __builtin_amdgcn_s_barrier();

  // steady state: 12 tiles, unrolled by 3 for static slot addressing
  for (int j = 0; j < 4; ++j) {
    const int t = j * 3;
    STAGE(t + 2, 98304); COMPUTE(0);     VMW(6); __builtin_amdgcn_s_barrier();
    STAGE(t + 3, 0);     COMPUTE(49152); VMW(6); __builtin_amdgcn_s_barrier();
    STAGE(t + 4, 49152); COMPUTE(98304); VMW(6); __builtin_amdgcn_s_barrier();
  }
  // tail: t=12..15 (slots 0,1,2,0)
  STAGE(14, 98304); COMPUTE(0); VMW(6); __builtin_amdgcn_s_barrier();
  STAGE(15, 0);     COMPUTE(49152); VMW(6); __builtin_amdgcn_s_barrier();
  COMPUTE(98304); VMW(0); __builtin_amdgcn_s_barrier();
  COMPUTE(0);
  __syncthreads();

  // ---- epilogue: 2 rounds x 2 d2-groups; slots [192][49] f32 ----
  float* fl = (float*)smem;                 // 2 x 9408 f32 = 75264 B
  float* ldacc = (float*)(smem + 75264);    // [192][4] f32
  #pragma unroll
  for (int r = 0; r < 2; ++r) {
    if ((wn >> 1) == r) {
      float* slot = fl + (wn & 1) * 9408;
      #pragma unroll
      for (int m = 0; m < 6; ++m)
        #pragma unroll
        for (int n = 0; n < 3; ++n)
          #pragma unroll
          for (int q = 0; q < 4; ++q)
            slot[(wm * 96 + m * 16 + fg * 4 + q) * 49 + n * 16 + fr] = acc[m][n][q];
    }
    __syncthreads();
    if (tid < 384) {
      const int g01 = (tid >= 192) ? 1 : 0;
      const int rr = tid - g01 * 192;
      const int grow = brow + rr;
      const int d2 = bn * 4 + r * 2 + g01;
      const float* pr = fl + g01 * 9408 + rr * 49;
      const float* bb = b2 + (size_t)d2 * 47;

      float wv[16], hv[16];
      #pragma unroll
      for (int j = 0; j < 16; ++j) wv[j] = pr[j] + bb[j];
      #pragma unroll
      for (int j = 0; j < 16; ++j) hv[j] = pr[16 + j] + bb[16 + j];

      float x = (grow < 16384) ? x2[(size_t)grow * 256 + d2] : 0.f;
      float xc = fminf(fmaxf(x, -3.f), 3.f);

      float mw = wv[0];
      #pragma unroll
      for (int j = 1; j < 16; ++j) mw = fmaxf(mw, wv[j]);
      float sw = 0.f;
      #pragma unroll
      for (int j = 0; j < 16; ++j) { wv[j] = __expf(wv[j] - mw); sw += wv[j]; }
      float scw = 0.984f / sw;

      float mh = hv[0];
      #pragma unroll
      for (int j = 1; j < 16; ++j) mh = fmaxf(mh, hv[j]);
      float sh = 0.f;
      #pragma unroll
      for (int j = 0; j < 16; ++j) { hv[j] = __expf(hv[j] - mh); sh += hv[j]; }
      float sch = 0.984f / sh;

      int idx = 0;
      float xk = -3.f, cum = 0.f;
      #pragma unroll
      for (int i = 1; i <= 15; ++i) {
        cum += 0.001f + wv[i - 1] * scw;
        float cwi = 6.f * cum - 3.f;
        if (xc >= cwi) { idx = i; xk = cwi; }
      }
      float yk = -3.f, cumh = 0.f;
      #pragma unroll
      for (int i = 1; i <= 15; ++i) {
        cumh += 0.001f + hv[i - 1] * sch;
        float chi = 6.f * cumh - 3.f;
        if (i == idx) yk = chi;
      }
      float wk = 1.f, hk = 1.f;
      #pragma unroll
      for (int i = 0; i < 16; ++i) {
        if (i == idx) {
          wk = 6.f * (0.001f + wv[i] * scw);
          hk = 6.f * (0.001f + hv[i] * sch);
        }
      }
      float dk = 1.f, dk1 = 1.f;
      #pragma unroll
      for (int i = 1; i <= 15; ++i) {
        float u = pr[32 + i - 1] + bb[32 + i - 1];
        float e = __expf(u);
        float dd = 0.001f + (u > 15.f ? u : log1pf(e));
        if (i == idx) dk = dd;
        if (i == idx + 1) dk1 = dd;
      }

      float sk = hk / wk;
      float th = (xc - xk) / wk;
      float om = 1.f - th;
      float t1m = th * om;
      float den = sk + (dk + dk1 - 2.f * sk) * t1m;
      float y = yk + hk * (sk * th * th + dk * t1m) / den;
      float deriv = sk * sk * (dk1 * th * th + 2.f * sk * t1m + dk * om * om) / (den * den);
      bool inside = (x > -3.f) && (x < 3.f);
      float yout = inside ? y : x;
      float ld = inside ? __logf(deriv) : 0.f;

      if (grow < 16384) {
        y2[(size_t)grow * 256 + d2] = yout;
        ldacc[rr * 4 + r * 2 + g01] = ld;
      }
    }
    __syncthreads();
  }

  if (tid < 192) {
    int grow = brow + tid;
    if (grow < 16384) {
      float s = ldacc[tid * 4] + ldacc[tid * 4 + 1] + ldacc[tid * 4 + 2] + ldacc[tid * 4 + 3];
      ldpart[(size_t)bn * 16384 + grow] = s;
    }
  }
}

__global__ void k_reduce_ld(const float* __restrict__ part, float* __restrict__ out) {
  int r = blockIdx.x * 256 + threadIdx.x;
  float s = 0.f;
  for (int j = 0; j < 64; ++j) s += part[(size_t)j * 16384 + r];
  out[r] = s;
}

// ---------------- launch ----------------
extern "C" void kernel_launch(void* const* d_in, const int* in_sizes, int n_in,
                              void* d_out, int out_size, void* d_ws, size_t ws_size,
                              hipStream_t stream) {
  const float* x1 = (const float*)d_in[0];
  const float* x2 = (const float*)d_in[1];
  const float* W0 = (const float*)d_in[2];
  const float* b0 = (const float*)d_in[3];
  const float* W1 = (const float*)d_in[4];
  const float* b1 = (const float*)d_in[5];
  const float* W2 = (const float*)d_in[6];
  const float* b2 = (const float*)d_in[7];
  float* y2 = (float*)d_out;
  float* logdet = y2 + (size_t)16384 * 256;

  char* ws = (char*)d_ws;
  u16* W2t = (u16*)ws;                                   // 25165824
  u16* W0t = (u16*)(ws + 25165824);                      //   524288
  u16* W1t = (u16*)(ws + 25165824 + 524288);             //  2097152
  u16* x1b = (u16*)(ws + 27787264);                      //  8388608
  float* ldp = (float*)(ws + 27787264);                  // aliases x1b (dead by GEMM3); 64*16384*4=4MB
  u16* h1  = (u16*)(ws + 36175872);                      // 33554432
  u16* h2  = (u16*)(ws + 69730304);                      // 33554432

  hipFuncSetAttribute((const void*)k_gemm3_fused,
                      hipFuncAttributeMaxDynamicSharedMemorySize, 147456);

  k_conv_bf16<<<16384, 256, 0, stream>>>(x1, x1b, 16384 * 256);
  k_transconv<<<dim3(8, 32), 256, 0, stream>>>(W0, W0t, 256, 1024, 1024, 0);
  k_transconv<<<dim3(32, 32), 256, 0, stream>>>(W1, W1t, 1024, 1024, 1024, 0);
  k_transconv<<<dim3(32, 384), 256, 0, stream>>>(W2, W2t, 1024, 12032, 12288, 1);

  k_gemm_relu<<<dim3(8, 128), 256, 0, stream>>>(x1b, W0t, b0, h1, 1024, 256);
  k_gemm_relu<<<dim3(8, 128), 256, 0, stream>>>(h1, W1t, b1, h2, 1024, 1024);
  k_gemm3_fused<<<5504, 512, 147456, stream>>>(h2, W2t, b2, x2, y2, ldp);
  k_reduce_ld<<<64, 256, 0, stream>>>(ldp, logdet);
}

// Round 9
// 752.409 us; speedup vs baseline: 1.1819x; 1.1819x over previous
//
#include <hip/hip_runtime.h>
#include <math.h>

using u16 = unsigned short;
using bf16x8 = __attribute__((ext_vector_type(8))) short;
using f32x4  = __attribute__((ext_vector_type(4))) float;

#define DEV static __device__ __forceinline__

DEV u16 f2bf(float f) {
  union { float f; unsigned u; } v; v.f = f;
  unsigned u = v.u + 0x7fffu + ((v.u >> 16) & 1u);
  return (u16)(u >> 16);
}

DEV void gload16(const void* g, void* l) {
  __builtin_amdgcn_global_load_lds(
      (const __attribute__((address_space(1))) void*)g,
      (__attribute__((address_space(3))) void*)l, 16, 0, 0);
}

// ---------------- prep kernels ----------------
__global__ void k_conv_bf16(const float* __restrict__ in, u16* __restrict__ out, int n) {
  int i = blockIdx.x * 256 + threadIdx.x;
  if (i < n) out[i] = f2bf(in[i]);
}

// in: f32 [K][Nin] row-major ; out: bf16 [Nout][K] (n-major).
// pack==1: n' = d2*48+j maps to n = d2*47+j for j<47, j==47 -> 0 (pad).
__global__ void k_transconv(const float* __restrict__ in, u16* __restrict__ out,
                            int K, int Nin, int Nout, int pack) {
  __shared__ float t[32][33];
  int kb = blockIdx.x * 32, nb = blockIdx.y * 32;
  int tx = threadIdx.x & 31, ty = threadIdx.x >> 5;  // 32 x 8
  #pragma unroll
  for (int i = 0; i < 4; ++i) {
    int k = kb + ty + i * 8;
    int no = nb + tx;
    float v = 0.f;
    if (k < K && no < Nout) {
      if (pack) {
        int r = no % 48;
        if (r < 47) v = in[(size_t)k * Nin + (no / 48) * 47 + r];
      } else {
        v = in[(size_t)k * Nin + no];
      }
    }
    t[ty + i * 8][tx] = v;
  }
  __syncthreads();
  #pragma unroll
  for (int i = 0; i < 4; ++i) {
    int no = nb + ty + i * 8;
    int k = kb + tx;
    if (no < Nout && k < K) out[(size_t)no * K + k] = f2bf(t[tx][ty + i * 8]);
  }
}

// ---------------- GEMM + ReLU (BM=128,BN=128,BK=32, 4 waves) for GEMM1/2 ----------------
__global__ __launch_bounds__(256)
void k_gemm_relu(const u16* __restrict__ A, const u16* __restrict__ Bt,
                 const float* __restrict__ bias, u16* __restrict__ C,
                 int N, int K) {
  constexpr int BM = 128, BN = 128, BK = 32;
  __shared__ __align__(16) u16 lds[(BM + BN) * BK];
  int tid = threadIdx.x, w = tid >> 6, lane = tid & 63;
  int bn = blockIdx.x, bm = blockIdx.y;
  int brow = bm * BM, bcol = bn * BN;
  int wm = w >> 1, wn = w & 1;
  int fr = lane & 15, fg = lane >> 4;
  f32x4 acc[4][4];
  #pragma unroll
  for (int i = 0; i < 4; ++i)
    #pragma unroll
    for (int j = 0; j < 4; ++j) acc[i][j] = (f32x4){0.f, 0.f, 0.f, 0.f};

  constexpr int ACH = BM * BK / 8;
  constexpr int CALLS = (BM + BN) * BK / 8 / 64;

  for (int kt = 0; kt < K; kt += BK) {
    for (int j = 0; j * 4 + w < CALLS; ++j) {
      int cb = (j * 4 + w) * 64;
      int c = cb + lane;
      const u16* g;
      if (c < ACH) {
        int row = c >> 2, c8 = c & 3;
        g = A + (size_t)(brow + row) * K + kt + c8 * 8;
      } else {
        int b = c - ACH;
        int nn = b >> 2, c8 = b & 3;
        g = Bt + (size_t)(bcol + nn) * K + kt + c8 * 8;
      }
      gload16(g, &lds[cb * 8]);
    }
    asm volatile("s_waitcnt vmcnt(0)" ::: "memory");
    __syncthreads();

    const u16* Al = lds;
    const u16* Bl = lds + BM * BK;
    bf16x8 af[4], bfr[4];
    #pragma unroll
    for (int mi = 0; mi < 4; ++mi)
      af[mi] = *(const bf16x8*)&Al[(wm * 64 + mi * 16 + fr) * BK + fg * 8];
    #pragma unroll
    for (int ni = 0; ni < 4; ++ni)
      bfr[ni] = *(const bf16x8*)&Bl[(wn * 64 + ni * 16 + fr) * BK + fg * 8];
    #pragma unroll
    for (int mi = 0; mi < 4; ++mi)
      #pragma unroll
      for (int ni = 0; ni < 4; ++ni)
        acc[mi][ni] = __builtin_amdgcn_mfma_f32_16x16x32_bf16(af[mi], bfr[ni], acc[mi][ni], 0, 0, 0);
    __syncthreads();
  }

  #pragma unroll
  for (int ni = 0; ni < 4; ++ni) {
    int col = bcol + wn * 64 + ni * 16 + fr;
    float bb = bias[col];
    #pragma unroll
    for (int mi = 0; mi < 4; ++mi) {
      #pragma unroll
      for (int q = 0; q < 4; ++q) {
        int row = brow + wm * 64 + mi * 16 + fg * 4 + q;
        float vv = acc[mi][ni][q] + bb;
        C[(size_t)row * N + col] = f2bf(vv > 0.f ? vv : 0.f);
      }
    }
  }
}

// ------- GEMM3 fused with spline: BM=256, BN=192, BK=64, 4 waves, A-direct-to-VGPR -------
// B-only LDS: dbuf 2x24576 ([192][64] bf16, R7-proven XOR chunk swizzle). A fragments
// loaded global->VGPR per lane (row=...+fr picks row, fg*8 picks k; 4 lanes/row = 64B
// contiguous; A panels L2-hot under XCD map). Each of 4 waves owns 64 rows x all 192
// cols: acc[4][12] (192 VGPR), a[4][2] frags. Traffic: A 64x33.5MB + B 64x25.2MB =
// 3.75GB (0.71x R7), and A bypasses the LDS-DMA path.
// Loop (R7-proven depth-1): issue 6 B-DMA(t+1) at top; compute (24 ds_read_b128,
// 96 MFMA); issue 8 A-loads(t+1) at end; vmcnt(0)+barrier. 2 blocks/CU (LDS 54272).
__global__ __launch_bounds__(256, 2)
void k_gemm3_fused(const u16* __restrict__ A, const u16* __restrict__ Bt,
                   const float* __restrict__ b2, const float* __restrict__ x2,
                   float* __restrict__ y2, float* __restrict__ ldpart) {
  extern __shared__ char smem[];
  const int tid = threadIdx.x, w = tid >> 6, lane = tid & 63;
  const int fr = lane & 15, fg = lane >> 4;

  const int bid = blockIdx.x;                          // 4096 blocks = 64 bm x 64 bn
  const int bm = bid >> 6;
  const int bn = ((bid & 7) << 3) | ((bid >> 3) & 7);  // XCD-chunked L2 map (R5-proven)
  const int brow = bm * 256;

  // ---- B staging (R7 pattern): row = (tid>>3)+32k, chunk = tid&7, source pre-XOR'd ----
  const int csrc = (tid & 7) ^ ((tid >> 3) & 7);
  const u16* gB[6];
  #pragma unroll
  for (int k = 0; k < 6; ++k)
    gB[k] = Bt + (size_t)(bn * 192 + (tid >> 3) + 32 * k) * 1024 + csrc * 8;

#define ISSUE_B(t1) {                                                 \
    const size_t ko_ = (size_t)(t1) * 64;                             \
    char* pb_ = smem + ((t1) & 1) * 24576;                            \
    gload16(gB[0] + ko_, pb_ + tid * 16);                             \
    gload16(gB[1] + ko_, pb_ + tid * 16 + 4096);                      \
    gload16(gB[2] + ko_, pb_ + tid * 16 + 8192);                      \
    gload16(gB[3] + ko_, pb_ + tid * 16 + 12288);                     \
    gload16(gB[4] + ko_, pb_ + tid * 16 + 16384);                     \
    gload16(gB[5] + ko_, pb_ + tid * 16 + 20480); }

  // ---- A direct-load bases: wave w owns rows [w*64, w*64+64) ----
  const u16* gAm[4];
  #pragma unroll
  for (int m = 0; m < 4; ++m)
    gAm[m] = A + (size_t)(brow + w * 64 + m * 16 + fr) * 1024 + fg * 8;

  // swizzled B-read chunk offsets: chunk = (kk*4+fg) ^ (row&7), row&7 == fr&7
  const int sc0 = ((fg ^ (fr & 7)) << 4);
  const int sc1 = (((4 + fg) ^ (fr & 7)) << 4);

  f32x4 acc[4][12];
  #pragma unroll
  for (int m = 0; m < 4; ++m)
    #pragma unroll
    for (int n = 0; n < 12; ++n) acc[m][n] = (f32x4){0.f, 0.f, 0.f, 0.f};

  bf16x8 a[4][2];

  // prologue: B tile 0 + A tile 0
  ISSUE_B(0);
  #pragma unroll
  for (int m = 0; m < 4; ++m) {
    a[m][0] = *(const bf16x8*)(gAm[m]);
    a[m][1] = *(const bf16x8*)(gAm[m] + 32);
  }
  asm volatile("s_waitcnt vmcnt(0)" ::: "memory");
  __syncthreads();

  for (int t = 0; t < 16; ++t) {
    if (t < 15) ISSUE_B(t + 1);
    const char* Bb = smem + (t & 1) * 24576;
    __builtin_amdgcn_s_setprio(1);
    #pragma unroll
    for (int kk = 0; kk < 2; ++kk) {
      const int sc = kk ? sc1 : sc0;
      #pragma unroll
      for (int n = 0; n < 12; ++n) {
        bf16x8 b = *(const bf16x8*)(Bb + (n * 16 + fr) * 128 + sc);
        #pragma unroll
        for (int m = 0; m < 4; ++m)
          acc[m][n] = __builtin_amdgcn_mfma_f32_16x16x32_bf16(a[m][kk], b, acc[m][n], 0, 0, 0);
      }
    }
    __builtin_amdgcn_s_setprio(0);
    if (t < 15) {
      const size_t ko = (size_t)(t + 1) * 64;
      #pragma unroll
      for (int m = 0; m < 4; ++m) {
        a[m][0] = *(const bf16x8*)(gAm[m] + ko);
        a[m][1] = *(const bf16x8*)(gAm[m] + ko + 32);
      }
      asm volatile("s_waitcnt vmcnt(0)" ::: "memory");
      __syncthreads();
    }
  }
  __syncthreads();

  // ---- epilogue: 4 rounds, one d2-group each; slot [256][49] f32 ----
  float* slot = (float*)smem;               // 50176 B
  float* ldacc = (float*)(smem + 50176);    // [256][4] f32
  #pragma unroll
  for (int g = 0; g < 4; ++g) {
    #pragma unroll
    for (int m = 0; m < 4; ++m)
      #pragma unroll
      for (int j = 0; j < 3; ++j) {
        const int n = g * 3 + j;
        #pragma unroll
        for (int q = 0; q < 4; ++q)
          slot[(w * 64 + m * 16 + fg * 4 + q) * 49 + j * 16 + fr] = acc[m][n][q];
      }
    __syncthreads();
    {
      const int r = tid;
      const float* pr = slot + r * 49;
      const int grow = brow + r;
      const int d2 = bn * 4 + g;
      const float* bb = b2 + (size_t)d2 * 47;

      float wv[16], hv[16];
      #pragma unroll
      for (int j = 0; j < 16; ++j) wv[j] = pr[j] + bb[j];
      #pragma unroll
      for (int j = 0; j < 16; ++j) hv[j] = pr[16 + j] + bb[16 + j];

      float x = x2[(size_t)grow * 256 + d2];
      float xc = fminf(fmaxf(x, -3.f), 3.f);

      float mw = wv[0];
      #pragma unroll
      for (int j = 1; j < 16; ++j) mw = fmaxf(mw, wv[j]);
      float sw = 0.f;
      #pragma unroll
      for (int j = 0; j < 16; ++j) { wv[j] = __expf(wv[j] - mw); sw += wv[j]; }
      float scw = 0.984f / sw;

      float mh = hv[0];
      #pragma unroll
      for (int j = 1; j < 16; ++j) mh = fmaxf(mh, hv[j]);
      float sh = 0.f;
      #pragma unroll
      for (int j = 0; j < 16; ++j) { hv[j] = __expf(hv[j] - mh); sh += hv[j]; }
      float sch = 0.984f / sh;

      int idx = 0;
      float xk = -3.f, cum = 0.f;
      #pragma unroll
      for (int i = 1; i <= 15; ++i) {
        cum += 0.001f + wv[i - 1] * scw;
        float cwi = 6.f * cum - 3.f;
        if (xc >= cwi) { idx = i; xk = cwi; }
      }
      float yk = -3.f, cumh = 0.f;
      #pragma unroll
      for (int i = 1; i <= 15; ++i) {
        cumh += 0.001f + hv[i - 1] * sch;
        float chi = 6.f * cumh - 3.f;
        if (i == idx) yk = chi;
      }
      float wk = 1.f, hk = 1.f;
      #pragma unroll
      for (int i = 0; i < 16; ++i) {
        if (i == idx) {
          wk = 6.f * (0.001f + wv[i] * scw);
          hk = 6.f * (0.001f + hv[i] * sch);
        }
      }
      float dk = 1.f, dk1 = 1.f;
      #pragma unroll
      for (int i = 1; i <= 15; ++i) {
        float u = pr[32 + i - 1] + bb[32 + i - 1];
        float e = __expf(u);
        float dd = 0.001f + (u > 15.f ? u : log1pf(e));
        if (i == idx) dk = dd;
        if (i == idx + 1) dk1 = dd;
      }

      float sk = hk / wk;
      float th = (xc - xk) / wk;
      float om = 1.f - th;
      float t1m = th * om;
      float den = sk + (dk + dk1 - 2.f * sk) * t1m;
      float y = yk + hk * (sk * th * th + dk * t1m) / den;
      float deriv = sk * sk * (dk1 * th * th + 2.f * sk * t1m + dk * om * om) / (den * den);
      bool inside = (x > -3.f) && (x < 3.f);
      float yout = inside ? y : x;
      float ld = inside ? __logf(deriv) : 0.f;

      y2[(size_t)grow * 256 + d2] = yout;
      ldacc[r * 4 + g] = ld;
    }
    __syncthreads();
  }

  {
    float s = ldacc[tid * 4] + ldacc[tid * 4 + 1] + ldacc[tid * 4 + 2] + ldacc[tid * 4 + 3];
    ldpart[(size_t)bn * 16384 + brow + tid] = s;
  }
}

__global__ void k_reduce_ld(const float* __restrict__ part, float* __restrict__ out) {
  int r = blockIdx.x * 256 + threadIdx.x;
  float s = 0.f;
  for (int j = 0; j < 64; ++j) s += part[(size_t)j * 16384 + r];
  out[r] = s;
}

// ---------------- launch ----------------
extern "C" void kernel_launch(void* const* d_in, const int* in_sizes, int n_in,
                              void* d_out, int out_size, void* d_ws, size_t ws_size,
                              hipStream_t stream) {
  const float* x1 = (const float*)d_in[0];
  const float* x2 = (const float*)d_in[1];
  const float* W0 = (const float*)d_in[2];
  const float* b0 = (const float*)d_in[3];
  const float* W1 = (const float*)d_in[4];
  const float* b1 = (const float*)d_in[5];
  const float* W2 = (const float*)d_in[6];
  const float* b2 = (const float*)d_in[7];
  float* y2 = (float*)d_out;
  float* logdet = y2 + (size_t)16384 * 256;

  char* ws = (char*)d_ws;
  u16* W2t = (u16*)ws;                                   // 25165824
  u16* W0t = (u16*)(ws + 25165824);                      //   524288
  u16* W1t = (u16*)(ws + 25165824 + 524288);             //  2097152
  u16* x1b = (u16*)(ws + 27787264);                      //  8388608
  float* ldp = (float*)(ws + 27787264);                  // aliases x1b (dead by GEMM3); 64*16384*4=4MB
  u16* h1  = (u16*)(ws + 36175872);                      // 33554432
  u16* h2  = (u16*)(ws + 69730304);                      // 33554432

  hipFuncSetAttribute((const void*)k_gemm3_fused,
                      hipFuncAttributeMaxDynamicSharedMemorySize, 54272);

  k_conv_bf16<<<16384, 256, 0, stream>>>(x1, x1b, 16384 * 256);
  k_transconv<<<dim3(8, 32), 256, 0, stream>>>(W0, W0t, 256, 1024, 1024, 0);
  k_transconv<<<dim3(32, 32), 256, 0, stream>>>(W1, W1t, 1024, 1024, 1024, 0);
  k_transconv<<<dim3(32, 384), 256, 0, stream>>>(W2, W2t, 1024, 12032, 12288, 1);

  k_gemm_relu<<<dim3(8, 128), 256, 0, stream>>>(x1b, W0t, b0, h1, 1024, 256);
  k_gemm_relu<<<dim3(8, 128), 256, 0, stream>>>(h1, W1t, b1, h2, 1024, 1024);
  k_gemm3_fused<<<4096, 256, 54272, stream>>>(h2, W2t, b2, x2, y2, ldp);
  k_reduce_ld<<<64, 256, 0, stream>>>(ldp, logdet);
}

// Round 10
// 741.836 us; speedup vs baseline: 1.1988x; 1.0143x over previous
//
#include <hip/hip_runtime.h>
#include <math.h>

using u16 = unsigned short;
using bf16x8 = __attribute__((ext_vector_type(8))) short;
using f32x4  = __attribute__((ext_vector_type(4))) float;

#define DEV static __device__ __forceinline__

DEV u16 f2bf(float f) {
  union { float f; unsigned u; } v; v.f = f;
  unsigned u = v.u + 0x7fffu + ((v.u >> 16) & 1u);
  return (u16)(u >> 16);
}

DEV void gload16(const void* g, void* l) {
  __builtin_amdgcn_global_load_lds(
      (const __attribute__((address_space(1))) void*)g,
      (__attribute__((address_space(3))) void*)l, 16, 0, 0);
}

// ---------------- prep kernels ----------------
__global__ void k_conv_bf16(const float* __restrict__ in, u16* __restrict__ out, int n) {
  int i = blockIdx.x * 256 + threadIdx.x;
  if (i < n) out[i] = f2bf(in[i]);
}

// in: f32 [K][Nin] row-major ; out: bf16 [Nout][K] (n-major).
// pack==1: n' = d2*48+j maps to n = d2*47+j for j<47, j==47 -> 0 (pad).
__global__ void k_transconv(const float* __restrict__ in, u16* __restrict__ out,
                            int K, int Nin, int Nout, int pack) {
  __shared__ float t[32][33];
  int kb = blockIdx.x * 32, nb = blockIdx.y * 32;
  int tx = threadIdx.x & 31, ty = threadIdx.x >> 5;  // 32 x 8
  #pragma unroll
  for (int i = 0; i < 4; ++i) {
    int k = kb + ty + i * 8;
    int no = nb + tx;
    float v = 0.f;
    if (k < K && no < Nout) {
      if (pack) {
        int r = no % 48;
        if (r < 47) v = in[(size_t)k * Nin + (no / 48) * 47 + r];
      } else {
        v = in[(size_t)k * Nin + no];
      }
    }
    t[ty + i * 8][tx] = v;
  }
  __syncthreads();
  #pragma unroll
  for (int i = 0; i < 4; ++i) {
    int no = nb + ty + i * 8;
    int k = kb + tx;
    if (no < Nout && k < K) out[(size_t)no * K + k] = f2bf(t[tx][ty + i * 8]);
  }
}

// ---------------- GEMM + ReLU (BM=128,BN=128,BK=32, 4 waves) for GEMM1/2 ----------------
__global__ __launch_bounds__(256)
void k_gemm_relu(const u16* __restrict__ A, const u16* __restrict__ Bt,
                 const float* __restrict__ bias, u16* __restrict__ C,
                 int N, int K) {
  constexpr int BM = 128, BN = 128, BK = 32;
  __shared__ __align__(16) u16 lds[(BM + BN) * BK];
  int tid = threadIdx.x, w = tid >> 6, lane = tid & 63;
  int bn = blockIdx.x, bm = blockIdx.y;
  int brow = bm * BM, bcol = bn * BN;
  int wm = w >> 1, wn = w & 1;
  int fr = lane & 15, fg = lane >> 4;
  f32x4 acc[4][4];
  #pragma unroll
  for (int i = 0; i < 4; ++i)
    #pragma unroll
    for (int j = 0; j < 4; ++j) acc[i][j] = (f32x4){0.f, 0.f, 0.f, 0.f};

  constexpr int ACH = BM * BK / 8;
  constexpr int CALLS = (BM + BN) * BK / 8 / 64;

  for (int kt = 0; kt < K; kt += BK) {
    for (int j = 0; j * 4 + w < CALLS; ++j) {
      int cb = (j * 4 + w) * 64;
      int c = cb + lane;
      const u16* g;
      if (c < ACH) {
        int row = c >> 2, c8 = c & 3;
        g = A + (size_t)(brow + row) * K + kt + c8 * 8;
      } else {
        int b = c - ACH;
        int nn = b >> 2, c8 = b & 3;
        g = Bt + (size_t)(bcol + nn) * K + kt + c8 * 8;
      }
      gload16(g, &lds[cb * 8]);
    }
    asm volatile("s_waitcnt vmcnt(0)" ::: "memory");
    __syncthreads();

    const u16* Al = lds;
    const u16* Bl = lds + BM * BK;
    bf16x8 af[4], bfr[4];
    #pragma unroll
    for (int mi = 0; mi < 4; ++mi)
      af[mi] = *(const bf16x8*)&Al[(wm * 64 + mi * 16 + fr) * BK + fg * 8];
    #pragma unroll
    for (int ni = 0; ni < 4; ++ni)
      bfr[ni] = *(const bf16x8*)&Bl[(wn * 64 + ni * 16 + fr) * BK + fg * 8];
    #pragma unroll
    for (int mi = 0; mi < 4; ++mi)
      #pragma unroll
      for (int ni = 0; ni < 4; ++ni)
        acc[mi][ni] = __builtin_amdgcn_mfma_f32_16x16x32_bf16(af[mi], bfr[ni], acc[mi][ni], 0, 0, 0);
    __syncthreads();
  }

  #pragma unroll
  for (int ni = 0; ni < 4; ++ni) {
    int col = bcol + wn * 64 + ni * 16 + fr;
    float bb = bias[col];
    #pragma unroll
    for (int mi = 0; mi < 4; ++mi) {
      #pragma unroll
      for (int q = 0; q < 4; ++q) {
        int row = brow + wm * 64 + mi * 16 + fg * 4 + q;
        float vv = acc[mi][ni][q] + bb;
        C[(size_t)row * N + col] = f2bf(vv > 0.f ? vv : 0.f);
      }
    }
  }
}

// ------- GEMM3 fused with spline: BM=128, BN=192, BK=64, 4 waves, 3 BLOCKS/CU -------
// B-only LDS dbuf 2x24576 (R7-proven XOR chunk swizzle); A direct global->VGPR
// (R9 pattern; wave w owns rows [w*32,w*32+32), acc[2][12]). LDS request 50176 ->
// floor(163840/50176)=3 blocks/CU = 12 waves (the m97 overlap regime).
// Loop: ISSUE_B(t+1) at top; kk0 MFMAs; reload a[*][0](t+1); kk1 MFMAs; reload
// a[*][1](t+1); vmcnt(4) (drains the 6 B-DMAs only -- compiler auto-waitcnt covers
// the 4 A-loads across the barrier, no exposed A latency); barrier.
// __launch_bounds__(256,4) pins VGPR<=128 (>128 would quantize waves/CU to 8 and
// kill the 3rd block, m69).
__global__ __launch_bounds__(256, 4)
void k_gemm3_fused(const u16* __restrict__ A, const u16* __restrict__ Bt,
                   const float* __restrict__ b2, const float* __restrict__ x2,
                   float* __restrict__ y2, float* __restrict__ ldpart) {
  extern __shared__ char smem[];
  const int tid = threadIdx.x, w = tid >> 6, lane = tid & 63;
  const int fr = lane & 15, fg = lane >> 4;

  const int bid = blockIdx.x;                          // 8192 blocks = 128 bm x 64 bn
  const int bm = bid >> 6;
  const int bn = ((bid & 7) << 3) | ((bid >> 3) & 7);  // XCD-chunked L2 map (R5-proven)
  const int brow = bm * 128;

  // ---- B staging (R7 pattern): row=(tid>>3)+32k, chunk=tid&7, source pre-XOR'd ----
  const int csrc = (tid & 7) ^ ((tid >> 3) & 7);
  const u16* gB0 = Bt + (size_t)(bn * 192 + (tid >> 3)) * 1024 + csrc * 8;

#define ISSUE_B(t1) {                                                 \
    const size_t ko_ = (size_t)(t1) * 64;                             \
    char* pb_ = smem + ((t1) & 1) * 24576 + tid * 16;                 \
    gload16(gB0 + ko_, pb_);                                          \
    gload16(gB0 + 32768 + ko_, pb_ + 4096);                           \
    gload16(gB0 + 65536 + ko_, pb_ + 8192);                           \
    gload16(gB0 + 98304 + ko_, pb_ + 12288);                          \
    gload16(gB0 + 131072 + ko_, pb_ + 16384);                         \
    gload16(gB0 + 163840 + ko_, pb_ + 20480); }

  // ---- A direct-load base: wave w owns rows [w*32, w*32+32); m offset = 16 rows ----
  const u16* gA0 = A + (size_t)(brow + w * 32 + fr) * 1024 + fg * 8;  // +32768 elems for m=1

  // swizzled B-read chunk offsets: chunk = (kk*4+fg) ^ (row&7), row&7 == fr&7
  const int sc0 = ((fg ^ (fr & 7)) << 4);
  const int sc1 = (((4 + fg) ^ (fr & 7)) << 4);

  f32x4 acc[2][12];
  #pragma unroll
  for (int m = 0; m < 2; ++m)
    #pragma unroll
    for (int n = 0; n < 12; ++n) acc[m][n] = (f32x4){0.f, 0.f, 0.f, 0.f};

  bf16x8 a[2][2];

  // prologue: B tile 0 + A tile 0
  ISSUE_B(0);
  a[0][0] = *(const bf16x8*)(gA0);
  a[0][1] = *(const bf16x8*)(gA0 + 32);
  a[1][0] = *(const bf16x8*)(gA0 + 16384);
  a[1][1] = *(const bf16x8*)(gA0 + 16384 + 32);
  asm volatile("s_waitcnt vmcnt(0)" ::: "memory");
  __syncthreads();

  for (int t = 0; t < 16; ++t) {
    if (t < 15) ISSUE_B(t + 1);
    const char* Bb = smem + (t & 1) * 24576;
    const size_t ko = (size_t)(t + 1) * 64;
    // kk0
    __builtin_amdgcn_s_setprio(1);
    #pragma unroll
    for (int n = 0; n < 12; ++n) {
      bf16x8 b = *(const bf16x8*)(Bb + (n * 16 + fr) * 128 + sc0);
      acc[0][n] = __builtin_amdgcn_mfma_f32_16x16x32_bf16(a[0][0], b, acc[0][n], 0, 0, 0);
      acc[1][n] = __builtin_amdgcn_mfma_f32_16x16x32_bf16(a[1][0], b, acc[1][n], 0, 0, 0);
    }
    __builtin_amdgcn_s_setprio(0);
    if (t < 15) {
      a[0][0] = *(const bf16x8*)(gA0 + ko);
      a[1][0] = *(const bf16x8*)(gA0 + 16384 + ko);
    }
    // kk1
    __builtin_amdgcn_s_setprio(1);
    #pragma unroll
    for (int n = 0; n < 12; ++n) {
      bf16x8 b = *(const bf16x8*)(Bb + (n * 16 + fr) * 128 + sc1);
      acc[0][n] = __builtin_amdgcn_mfma_f32_16x16x32_bf16(a[0][1], b, acc[0][n], 0, 0, 0);
      acc[1][n] = __builtin_amdgcn_mfma_f32_16x16x32_bf16(a[1][1], b, acc[1][n], 0, 0, 0);
    }
    __builtin_amdgcn_s_setprio(0);
    if (t < 15) {
      a[0][1] = *(const bf16x8*)(gA0 + ko + 32);
      a[1][1] = *(const bf16x8*)(gA0 + 16384 + ko + 32);
      asm volatile("s_waitcnt vmcnt(4)" ::: "memory");  // drain the 6 B-DMAs only
    }
    __builtin_amdgcn_s_barrier();
  }

  // ---- epilogue: 2 rounds x 2 groups; slots [2][128][49] f32 = 50176 B ----
  float* slotf = (float*)smem;
  const int h = tid >> 7, rrow = tid & 127;
  float ldsum = 0.f;
  #pragma unroll
  for (int r = 0; r < 2; ++r) {
    #pragma unroll
    for (int hh = 0; hh < 2; ++hh)
      #pragma unroll
      for (int m = 0; m < 2; ++m)
        #pragma unroll
        for (int j = 0; j < 3; ++j) {
          const int n = (r * 2 + hh) * 3 + j;
          #pragma unroll
          for (int q = 0; q < 4; ++q)
            slotf[hh * 6272 + (w * 32 + m * 16 + fg * 4 + q) * 49 + j * 16 + fr] = acc[m][n][q];
        }
    __syncthreads();
    {
      const float* pr = slotf + h * 6272 + rrow * 49;
      const int grow = brow + rrow;
      const int d2 = bn * 4 + r * 2 + h;
      const float* bb = b2 + (size_t)d2 * 47;

      float wv[16], hv[16];
      #pragma unroll
      for (int j = 0; j < 16; ++j) wv[j] = pr[j] + bb[j];
      #pragma unroll
      for (int j = 0; j < 16; ++j) hv[j] = pr[16 + j] + bb[16 + j];

      float x = x2[(size_t)grow * 256 + d2];
      float xc = fminf(fmaxf(x, -3.f), 3.f);

      float mw = wv[0];
      #pragma unroll
      for (int j = 1; j < 16; ++j) mw = fmaxf(mw, wv[j]);
      float sw = 0.f;
      #pragma unroll
      for (int j = 0; j < 16; ++j) { wv[j] = __expf(wv[j] - mw); sw += wv[j]; }
      float scw = 0.984f / sw;

      float mh = hv[0];
      #pragma unroll
      for (int j = 1; j < 16; ++j) mh = fmaxf(mh, hv[j]);
      float sh = 0.f;
      #pragma unroll
      for (int j = 0; j < 16; ++j) { hv[j] = __expf(hv[j] - mh); sh += hv[j]; }
      float sch = 0.984f / sh;

      int idx = 0;
      float xk = -3.f, cum = 0.f;
      #pragma unroll
      for (int i = 1; i <= 15; ++i) {
        cum += 0.001f + wv[i - 1] * scw;
        float cwi = 6.f * cum - 3.f;
        if (xc >= cwi) { idx = i; xk = cwi; }
      }
      float yk = -3.f, cumh = 0.f;
      #pragma unroll
      for (int i = 1; i <= 15; ++i) {
        cumh += 0.001f + hv[i - 1] * sch;
        float chi = 6.f * cumh - 3.f;
        if (i == idx) yk = chi;
      }
      float wk = 1.f, hk = 1.f;
      #pragma unroll
      for (int i = 0; i < 16; ++i) {
        if (i == idx) {
          wk = 6.f * (0.001f + wv[i] * scw);
          hk = 6.f * (0.001f + hv[i] * sch);
        }
      }
      float dk = 1.f, dk1 = 1.f;
      #pragma unroll
      for (int i = 1; i <= 15; ++i) {
        float u = pr[32 + i - 1] + bb[32 + i - 1];
        float e = __expf(u);
        float dd = 0.001f + (u > 15.f ? u : log1pf(e));
        if (i == idx) dk = dd;
        if (i == idx + 1) dk1 = dd;
      }

      float sk = hk / wk;
      float th = (xc - xk) / wk;
      float om = 1.f - th;
      float t1m = th * om;
      float den = sk + (dk + dk1 - 2.f * sk) * t1m;
      float y = yk + hk * (sk * th * th + dk * t1m) / den;
      float deriv = sk * sk * (dk1 * th * th + 2.f * sk * t1m + dk * om * om) / (den * den);
      bool inside = (x > -3.f) && (x < 3.f);
      float yout = inside ? y : x;
      float ld = inside ? __logf(deriv) : 0.f;

      y2[(size_t)grow * 256 + d2] = yout;
      ldsum += ld;
    }
    __syncthreads();
  }

  ldpart[(size_t)(bn * 2 + h) * 16384 + brow + rrow] = ldsum;
}

__global__ void k_reduce_ld(const float* __restrict__ part, float* __restrict__ out) {
  int r = blockIdx.x * 256 + threadIdx.x;
  float s = 0.f;
  for (int j = 0; j < 128; ++j) s += part[(size_t)j * 16384 + r];
  out[r] = s;
}

// ---------------- launch ----------------
extern "C" void kernel_launch(void* const* d_in, const int* in_sizes, int n_in,
                              void* d_out, int out_size, void* d_ws, size_t ws_size,
                              hipStream_t stream) {
  const float* x1 = (const float*)d_in[0];
  const float* x2 = (const float*)d_in[1];
  const float* W0 = (const float*)d_in[2];
  const float* b0 = (const float*)d_in[3];
  const float* W1 = (const float*)d_in[4];
  const float* b1 = (const float*)d_in[5];
  const float* W2 = (const float*)d_in[6];
  const float* b2 = (const float*)d_in[7];
  float* y2 = (float*)d_out;
  float* logdet = y2 + (size_t)16384 * 256;

  char* ws = (char*)d_ws;
  u16* W2t = (u16*)ws;                                   // 25165824
  u16* W0t = (u16*)(ws + 25165824);                      //   524288
  u16* W1t = (u16*)(ws + 25165824 + 524288);             //  2097152
  u16* x1b = (u16*)(ws + 27787264);                      //  8388608
  float* ldp = (float*)(ws + 27787264);                  // aliases x1b (dead by GEMM3); 128*16384*4=8388608
  u16* h1  = (u16*)(ws + 36175872);                      // 33554432
  u16* h2  = (u16*)(ws + 69730304);                      // 33554432

  hipFuncSetAttribute((const void*)k_gemm3_fused,
                      hipFuncAttributeMaxDynamicSharedMemorySize, 50176);

  k_conv_bf16<<<16384, 256, 0, stream>>>(x1, x1b, 16384 * 256);
  k_transconv<<<dim3(8, 32), 256, 0, stream>>>(W0, W0t, 256, 1024, 1024, 0);
  k_transconv<<<dim3(32, 32), 256, 0, stream>>>(W1, W1t, 1024, 1024, 1024, 0);
  k_transconv<<<dim3(32, 384), 256, 0, stream>>>(W2, W2t, 1024, 12032, 12288, 1);

  k_gemm_relu<<<dim3(8, 128), 256, 0, stream>>>(x1b, W0t, b0, h1, 1024, 256);
  k_gemm_relu<<<dim3(8, 128), 256, 0, stream>>>(h1, W1t, b1, h2, 1024, 1024);
  k_gemm3_fused<<<8192, 256, 50176, stream>>>(h2, W2t, b2, x2, y2, ldp);
  k_reduce_ld<<<64, 256, 0, stream>>>(ldp, logdet);
}